// Round 1
// baseline (271.367 us; speedup 1.0000x reference)
//
#include <hip/hip_runtime.h>

#define GSZ 640
#define NIMG 320
#define MS 102400
#define NC 12
#define BETA_F 13.8551004f
#define TWOPI_F 6.2831855f

// ---------- Bessel I0 (Abramowitz & Stegun 9.8.1 / 9.8.2, rel err < 2e-7) ----------
__device__ __forceinline__ float i0f(float x) {
    float ax = fabsf(x);
    if (ax < 3.75f) {
        float t = ax * (1.0f / 3.75f);
        t *= t;
        return 1.0f + t * (3.5156229f + t * (3.0899424f + t * (1.2067492f +
                     t * (0.2659732f + t * (0.0360768f + t * 0.0045813f)))));
    } else {
        float t = 3.75f / ax;
        float p = 0.39894228f + t * (0.01328592f + t * (0.00225319f + t * (-0.00157565f +
                  t * (0.00916281f + t * (-0.02057706f + t * (0.02635537f +
                  t * (-0.01647633f + t * 0.00392377f)))))));
        return p * expf(ax) / sqrtf(ax);
    }
}

// Kaiser-Bessel kernel, support |u| <= 3 (J=6)
__device__ __forceinline__ float kbval(float u) {
    float mm = fabsf(u) * (1.0f / 3.0f);
    float s = 1.0f - mm * mm;
    s = s > 0.0f ? s : 0.0f;
    float v = i0f(BETA_F * sqrtf(s)) * (1.0f / 6.0f);
    return (mm <= 1.0f) ? v : 0.0f;
}

// ---------- 640-point Stockham DIF FFT in LDS (radix-5 then 7x radix-2) ----------
// Input in bA, output (natural order) in bA. 320 threads, t in [0,320).
__device__ void fft640(float2* bA, float2* bB, int t) {
    // radix-5 stage: n=640, s=1, m=128
    if (t < 128) {
        float2 a0 = bA[t];
        float2 a1 = bA[t + 128];
        float2 a2 = bA[t + 256];
        float2 a3 = bA[t + 384];
        float2 a4 = bA[t + 512];
        // w5^k = exp(-2*pi*i*k/5)
        const float wr[5] = {1.0f, 0.30901699f, -0.80901699f, -0.80901699f, 0.30901699f};
        const float wi[5] = {0.0f, -0.95105652f, -0.58778525f, 0.58778525f, 0.95105652f};
        float2 aj[5] = {a0, a1, a2, a3, a4};
        #pragma unroll
        for (int r = 0; r < 5; ++r) {
            float br = a0.x, bi = a0.y;
            #pragma unroll
            for (int j = 1; j < 5; ++j) {
                int k = (j * r) % 5;
                br += aj[j].x * wr[k] - aj[j].y * wi[k];
                bi += aj[j].x * wi[k] + aj[j].y * wr[k];
            }
            float ang = (-TWOPI_F / 640.0f) * (float)(t * r);
            float sn, cs;
            sincosf(ang, &sn, &cs);
            bB[5 * t + r] = make_float2(br * cs - bi * sn, br * sn + bi * cs);
        }
    }
    __syncthreads();
    // 7 radix-2 stages: n = 128..2, s = 5..320  (m*s == 320 each stage)
    float2* src = bB;
    float2* dst = bA;
    int n = 128, s = 5;
    #pragma unroll
    for (int st = 0; st < 7; ++st) {
        int m = n >> 1;
        int p = t / s;
        int q = t - p * s;
        float2 a = src[q + s * p];
        float2 b = src[q + s * (p + m)];
        float ang = (-TWOPI_F) * (float)p / (float)n;
        float sn, cs;
        sincosf(ang, &sn, &cs);
        float dx = a.x - b.x, dy = a.y - b.y;
        dst[q + s * (2 * p)]     = make_float2(a.x + b.x, a.y + b.y);
        dst[q + s * (2 * p + 1)] = make_float2(dx * cs - dy * sn, dx * sn + dy * cs);
        float2* tmp = src; src = dst; dst = tmp;
        n = m;
        s <<= 1;
        __syncthreads();
    }
    // after 8 stages total, result is in bA
}

// ---------- apodization correction vector (len 320, H==W so one vector) ----------
__global__ void apod_kernel(float* __restrict__ a) {
    int n = threadIdx.x;  // 320 threads
    float apod = 0.0f;
    #pragma unroll
    for (int j = -3; j <= 3; ++j) {
        float kv = kbval((float)j);
        apod += kv * cosf((TWOPI_F * (float)j * ((float)n - 160.0f)) / 640.0f);
    }
    a[n] = 1.0f / apod;
}

// ---------- pass A: per (coil, nonzero-row ri) 640-pt FFT along columns ----------
// grid row r(ri) = ri<160 ? ri : ri+320 ; image row h = ri<160 ? ri+160 : ri-160
__global__ __launch_bounds__(320)
void passA_kernel(const float* __restrict__ img_r, const float* __restrict__ img_i,
                  const float* __restrict__ sm_r, const float* __restrict__ sm_i,
                  const float* __restrict__ apod, float2* __restrict__ Aout) {
    __shared__ float2 bA[GSZ], bB[GSZ];
    int ri = blockIdx.x, c = blockIdx.y, t = threadIdx.x;
    int h = (ri < 160) ? ri + 160 : ri - 160;
    int w = (t < 160) ? t + 160 : t - 160;
    float scale = apod[h] * apod[w] * (1.0f / 640.0f);  // includes 1/sqrt(G1*G2)
    float xr = img_r[h * NIMG + w];
    float xi = img_i[h * NIMG + w];
    float sr = sm_r[(c * NIMG + h) * NIMG + w];
    float si = sm_i[(c * NIMG + h) * NIMG + w];
    float vr = (xr * sr - xi * si) * scale;
    float vi = (xr * si + xi * sr) * scale;
    int vnz = (t < 160) ? t : t + 320;   // nonzero (ifftshifted) column position
    int vz  = (t < 160) ? t + 320 : t;   // the zero one this thread owns
    bA[vnz] = make_float2(vr, vi);
    bA[vz]  = make_float2(0.0f, 0.0f);
    __syncthreads();
    fft640(bA, bB, t);
    float2* out = Aout + (c * 320 + ri) * GSZ;
    out[t] = bA[t];
    out[t + 320] = bA[t + 320];
}

// ---------- pass B: per (coil, v) 640-pt FFT along rows; writes G[c][v][u] ----------
__global__ __launch_bounds__(320)
void passB_kernel(const float2* __restrict__ Ain, float2* __restrict__ Gout) {
    __shared__ float2 bA[GSZ], bB[GSZ];
    int v = blockIdx.x, c = blockIdx.y, t = threadIdx.x;
    float2 val = Ain[(c * 320 + t) * GSZ + v];   // ri == t in both halves
    int rnz = (t < 160) ? t : t + 320;
    int rz  = (t < 160) ? t + 320 : t;
    bA[rnz] = val;
    bA[rz]  = make_float2(0.0f, 0.0f);
    __syncthreads();
    fft640(bA, bB, t);
    float2* out = Gout + (c * GSZ + v) * GSZ;    // u contiguous
    out[t] = bA[t];
    out[t + 320] = bA[t + 320];
}

// ---------- KB tap weights + wrapped indices, matching jnp op order ----------
__device__ __forceinline__ void taps(float om, float* w, int* idx) {
    float t = fmodf((om * 640.0f) / TWOPI_F, 640.0f);
    if (t < 0.0f) t += 640.0f;
    float base = floorf(t);
    float frac = t - base;
    int ib = (int)base;
    #pragma unroll
    for (int j = 0; j < 6; ++j) {
        w[j] = kbval(frac + (float)(2 - j));  // u = t - (base + j - 2)
        int k = ib + j - 2;
        if (k < 0) k += GSZ;
        if (k >= GSZ) k -= GSZ;
        idx[j] = k;
    }
}

// ---------- interpolation: one thread per (coil, sample) ----------
__global__ __launch_bounds__(256)
void interp_kernel(const float* __restrict__ kt, const float2* __restrict__ Gg,
                   float2* __restrict__ out) {
    int tid = blockIdx.x * 256 + threadIdx.x;
    int c = tid / MS;
    int m = tid - c * MS;
    if (c >= NC) return;  // grid is exact (4800*256 == 12*102400)
    float w1[6], w2[6];
    int iu[6], iv[6];
    taps(kt[m], w1, iu);        // dim 1 -> u (rows)
    taps(kt[MS + m], w2, iv);   // dim 2 -> v (cols)
    const float2* Gc = Gg + c * (GSZ * GSZ);
    float ar = 0.0f, ai = 0.0f;
    #pragma unroll
    for (int j2 = 0; j2 < 6; ++j2) {
        const float2* Gv = Gc + iv[j2] * GSZ;
        float b2 = w2[j2];
        #pragma unroll
        for (int j1 = 0; j1 < 6; ++j1) {
            float2 g = Gv[iu[j1]];
            float ww = b2 * w1[j1];
            ar = fmaf(ww, g.x, ar);
            ai = fmaf(ww, g.y, ai);
        }
    }
    out[c * MS + m] = make_float2(ar, ai);
}

extern "C" void kernel_launch(void* const* d_in, const int* in_sizes, int n_in,
                              void* d_out, int out_size, void* d_ws, size_t ws_size,
                              hipStream_t stream) {
    const float* img_r = (const float*)d_in[0];
    const float* img_i = (const float*)d_in[1];
    const float* sm_r  = (const float*)d_in[2];
    const float* sm_i  = (const float*)d_in[3];
    const float* kt    = (const float*)d_in[4];

    char* ws = (char*)d_ws;
    float*  apod = (float*)ws;                                   // 320 floats
    float2* Abuf = (float2*)(ws + 2048);                         // 12*320*640*8 = 19,660,800 B
    float2* Gbuf = (float2*)(ws + 2048 + 12 * 320 * GSZ * 8);    // 12*640*640*8 = 39,321,600 B

    apod_kernel<<<1, 320, 0, stream>>>(apod);
    passA_kernel<<<dim3(320, NC), 320, 0, stream>>>(img_r, img_i, sm_r, sm_i, apod, Abuf);
    passB_kernel<<<dim3(GSZ, NC), 320, 0, stream>>>(Abuf, Gbuf);
    interp_kernel<<<4800, 256, 0, stream>>>(kt, Gbuf, (float2*)d_out);
}

// Round 2
// 227.389 us; speedup vs baseline: 1.1934x; 1.1934x over previous
//
#include <hip/hip_runtime.h>

#define GSZ 640
#define NIMG 320
#define MS 102400
#define NC 12
#define BETA_F 13.8551004f
#define TWOPI_F 6.2831855f

// ---------- Bessel I0 (Abramowitz & Stegun 9.8.1 / 9.8.2, rel err < 2e-7) ----------
__device__ __forceinline__ float i0f(float x) {
    float ax = fabsf(x);
    if (ax < 3.75f) {
        float t = ax * (1.0f / 3.75f);
        t *= t;
        return 1.0f + t * (3.5156229f + t * (3.0899424f + t * (1.2067492f +
                     t * (0.2659732f + t * (0.0360768f + t * 0.0045813f)))));
    } else {
        float t = 3.75f / ax;
        float p = 0.39894228f + t * (0.01328592f + t * (0.00225319f + t * (-0.00157565f +
                  t * (0.00916281f + t * (-0.02057706f + t * (0.02635537f +
                  t * (-0.01647633f + t * 0.00392377f)))))));
        return p * expf(ax) / sqrtf(ax);
    }
}

// Kaiser-Bessel kernel, support |u| <= 3 (J=6)
__device__ __forceinline__ float kbval(float u) {
    float mm = fabsf(u) * (1.0f / 3.0f);
    float s = 1.0f - mm * mm;
    s = s > 0.0f ? s : 0.0f;
    float v = i0f(BETA_F * sqrtf(s)) * (1.0f / 6.0f);
    return (mm <= 1.0f) ? v : 0.0f;
}

__device__ __forceinline__ float2 cmul(float2 a, float2 w) {
    return make_float2(a.x * w.x - a.y * w.y, a.x * w.y + a.y * w.x);
}

// Build 640-entry twiddle table tw[k] = exp(-2*pi*i*k/640) with 320 threads.
__device__ __forceinline__ void build_tw(float2* tw, int t) {
    float s0, c0;
    __sincosf((-TWOPI_F / 640.0f) * (float)t, &s0, &c0);
    tw[t] = make_float2(c0, s0);
    __sincosf((-TWOPI_F / 640.0f) * (float)(t + 320), &s0, &c0);
    tw[t + 320] = make_float2(c0, s0);
}

// ---------- 640-point Stockham DIF FFT in LDS (radix-5 then 7x radix-2) ----------
// Caller must __syncthreads() after filling bA and tw. Result in bA, natural order.
__device__ void fft640(float2* bA, float2* bB, const float2* tw, int t) {
    // radix-5 stage: n=640, s=1, m=128
    if (t < 128) {
        float2 aj[5];
        #pragma unroll
        for (int j = 0; j < 5; ++j) aj[j] = bA[t + 128 * j];
        const float wr[5] = {1.0f, 0.30901699f, -0.80901699f, -0.80901699f, 0.30901699f};
        const float wi[5] = {0.0f, -0.95105652f, -0.58778525f, 0.58778525f, 0.95105652f};
        #pragma unroll
        for (int r = 0; r < 5; ++r) {
            float br = aj[0].x, bi = aj[0].y;
            #pragma unroll
            for (int j = 1; j < 5; ++j) {
                int k = (j * r) % 5;
                br += aj[j].x * wr[k] - aj[j].y * wi[k];
                bi += aj[j].x * wi[k] + aj[j].y * wr[k];
            }
            float2 w = tw[t * r];  // t*r < 512
            bB[5 * t + r] = cmul(make_float2(br, bi), w);
        }
    }
    __syncthreads();
    // 7 radix-2 stages: n = 128..2, s = 5..320 ; w_n^p = tw[p * (640/n)]
    float2* src = bB;
    float2* dst = bA;
    int n = 128, s = 5, mult = 5;
    #pragma unroll
    for (int st = 0; st < 7; ++st) {
        int m = n >> 1;
        int p = t / s;
        int q = t - p * s;
        float2 a = src[q + s * p];
        float2 b = src[q + s * (p + m)];
        float2 w = tw[p * mult];
        float2 d = make_float2(a.x - b.x, a.y - b.y);
        dst[q + s * (2 * p)]     = make_float2(a.x + b.x, a.y + b.y);
        dst[q + s * (2 * p + 1)] = cmul(d, w);
        float2* tmp = src; src = dst; dst = tmp;
        n = m;
        s <<= 1;
        mult <<= 1;
        __syncthreads();
    }
    // 8 stages total -> result in bA
}

// ---------- apodization correction vector (len 320, H==W so one vector) ----------
__global__ void apod_kernel(float* __restrict__ a) {
    int n = threadIdx.x;  // 320 threads
    float apod = 0.0f;
    #pragma unroll
    for (int j = -3; j <= 3; ++j) {
        float kv = kbval((float)j);
        apod += kv * cosf((TWOPI_F * (float)j * ((float)n - 160.0f)) / 640.0f);
    }
    a[n] = 1.0f / apod;
}

// ---------- pass A: per (coil, nonzero-row ri) 640-pt FFT along columns ----------
// Writes TRANSPOSED: At[(c*640 + v)*320 + ri]  (scattered 8B writes, L2 merges)
__global__ __launch_bounds__(320)
void passA_kernel(const float* __restrict__ img_r, const float* __restrict__ img_i,
                  const float* __restrict__ sm_r, const float* __restrict__ sm_i,
                  const float* __restrict__ apod, float2* __restrict__ At) {
    __shared__ float2 bA[GSZ], bB[GSZ], tw[GSZ];
    int ri = blockIdx.x, c = blockIdx.y, t = threadIdx.x;
    build_tw(tw, t);
    int h = (ri < 160) ? ri + 160 : ri - 160;
    int w = (t < 160) ? t + 160 : t - 160;
    float scale = apod[h] * apod[w] * (1.0f / 640.0f);  // includes 1/sqrt(G1*G2)
    float xr = img_r[h * NIMG + w];
    float xi = img_i[h * NIMG + w];
    float sr = sm_r[(c * NIMG + h) * NIMG + w];
    float si = sm_i[(c * NIMG + h) * NIMG + w];
    float vr = (xr * sr - xi * si) * scale;
    float vi = (xr * si + xi * sr) * scale;
    int vnz = (t < 160) ? t : t + 320;   // nonzero (ifftshifted) column position
    int vz  = (t < 160) ? t + 320 : t;
    bA[vnz] = make_float2(vr, vi);
    bA[vz]  = make_float2(0.0f, 0.0f);
    __syncthreads();
    fft640(bA, bB, tw, t);
    // transposed store: column-major so passB reads coalesced
    At[(c * GSZ + t) * 320 + ri]         = bA[t];
    At[(c * GSZ + t + 320) * 320 + ri]   = bA[t + 320];
}

// ---------- pass B: per (coil, v) 640-pt FFT along rows ----------
// Reads coalesced from At; writes coil-interleaved G[v][u][c] (u-runs of 576B)
__global__ __launch_bounds__(320)
void passB_kernel(const float2* __restrict__ At, float2* __restrict__ Gout) {
    __shared__ float2 bA[GSZ], bB[GSZ], tw[GSZ];
    int v = blockIdx.x, c = blockIdx.y, t = threadIdx.x;
    build_tw(tw, t);
    float2 val = At[(c * GSZ + v) * 320 + t];   // contiguous in t
    int rnz = (t < 160) ? t : t + 320;
    int rz  = (t < 160) ? t + 320 : t;
    bA[rnz] = val;
    bA[rz]  = make_float2(0.0f, 0.0f);
    __syncthreads();
    fft640(bA, bB, tw, t);
    Gout[(v * GSZ + t) * NC + c]         = bA[t];
    Gout[(v * GSZ + t + 320) * NC + c]   = bA[t + 320];
}

// ---------- KB tap weights + wrapped indices ----------
__device__ __forceinline__ void taps(float om, float* w, int* idx) {
    float t = fmodf((om * 640.0f) / TWOPI_F, 640.0f);
    if (t < 0.0f) t += 640.0f;
    float base = floorf(t);
    float frac = t - base;
    int ib = (int)base;
    #pragma unroll
    for (int j = 0; j < 6; ++j) {
        w[j] = kbval(frac + (float)(2 - j));  // u = t - (base + j - 2)
        int k = ib + j - 2;
        if (k < 0) k += GSZ;
        if (k >= GSZ) k -= GSZ;
        idx[j] = k;
    }
}

// ---------- interpolation: 6 lanes per sample, 2 coils per lane ----------
// G layout: [v][u][c] float2, so one (v,u) position = 12 float2 = 96B contiguous;
// lane p loads coils {2p,2p+1} as one float4 (16B-aligned since 2p*8 % 16 == 0).
__global__ __launch_bounds__(256)
void interp_kernel(const float* __restrict__ kt, const float4* __restrict__ Gf,
                   float2* __restrict__ out) {
    int tid = blockIdx.x * 256 + threadIdx.x;   // 614400 = 2400*256 exactly
    int m = tid / 6;
    int p = tid - 6 * m;                        // coil pair index 0..5
    float w1[6], w2[6];
    int iu[6], iv[6];
    taps(kt[m], w1, iu);        // dim 0 -> u (row frequency)
    taps(kt[MS + m], w2, iv);   // dim 1 -> v (col frequency)
    float a0r = 0.0f, a0i = 0.0f, a1r = 0.0f, a1i = 0.0f;
    #pragma unroll
    for (int j2 = 0; j2 < 6; ++j2) {
        int rb = iv[j2] * (GSZ * NC / 2) + p;   // float4 index base for this v-row
        float b2 = w2[j2];
        #pragma unroll
        for (int j1 = 0; j1 < 6; ++j1) {
            float4 g = Gf[rb + iu[j1] * (NC / 2)];
            float ww = b2 * w1[j1];
            a0r = fmaf(ww, g.x, a0r);
            a0i = fmaf(ww, g.y, a0i);
            a1r = fmaf(ww, g.z, a1r);
            a1i = fmaf(ww, g.w, a1i);
        }
    }
    out[(2 * p) * MS + m]     = make_float2(a0r, a0i);
    out[(2 * p + 1) * MS + m] = make_float2(a1r, a1i);
}

extern "C" void kernel_launch(void* const* d_in, const int* in_sizes, int n_in,
                              void* d_out, int out_size, void* d_ws, size_t ws_size,
                              hipStream_t stream) {
    const float* img_r = (const float*)d_in[0];
    const float* img_i = (const float*)d_in[1];
    const float* sm_r  = (const float*)d_in[2];
    const float* sm_i  = (const float*)d_in[3];
    const float* kt    = (const float*)d_in[4];

    char* ws = (char*)d_ws;
    float*  apod = (float*)ws;                                   // 320 floats
    float2* Abuf = (float2*)(ws + 2048);                         // 12*640*320*8 = 19,660,800 B
    float2* Gbuf = (float2*)(ws + 2048 + 12 * 320 * GSZ * 8);    // 640*640*12*8 = 39,321,600 B

    apod_kernel<<<1, 320, 0, stream>>>(apod);
    passA_kernel<<<dim3(320, NC), 320, 0, stream>>>(img_r, img_i, sm_r, sm_i, apod, Abuf);
    passB_kernel<<<dim3(GSZ, NC), 320, 0, stream>>>(Abuf, Gbuf);
    interp_kernel<<<2400, 256, 0, stream>>>(kt, (const float4*)Gbuf, (float2*)d_out);
}

// Round 3
// 210.673 us; speedup vs baseline: 1.2881x; 1.0793x over previous
//
#include <hip/hip_runtime.h>

#define GSZ 640
#define NIMG 320
#define MS 102400
#define NC 12
#define BETA_F 13.8551004f
#define TWOPI_F 6.2831855f

// ---------- Bessel I0 (Abramowitz & Stegun 9.8.1 / 9.8.2, rel err < 2e-7) ----------
__device__ __forceinline__ float i0f(float x) {
    float ax = fabsf(x);
    if (ax < 3.75f) {
        float t = ax * (1.0f / 3.75f);
        t *= t;
        return 1.0f + t * (3.5156229f + t * (3.0899424f + t * (1.2067492f +
                     t * (0.2659732f + t * (0.0360768f + t * 0.0045813f)))));
    } else {
        float t = 3.75f / ax;
        float p = 0.39894228f + t * (0.01328592f + t * (0.00225319f + t * (-0.00157565f +
                  t * (0.00916281f + t * (-0.02057706f + t * (0.02635537f +
                  t * (-0.01647633f + t * 0.00392377f)))))));
        return p * expf(ax) / sqrtf(ax);
    }
}

// Kaiser-Bessel kernel, support |u| <= 3 (J=6)
__device__ __forceinline__ float kbval(float u) {
    float mm = fabsf(u) * (1.0f / 3.0f);
    float s = 1.0f - mm * mm;
    s = s > 0.0f ? s : 0.0f;
    float v = i0f(BETA_F * sqrtf(s)) * (1.0f / 6.0f);
    return (mm <= 1.0f) ? v : 0.0f;
}

__device__ __forceinline__ float2 cmul(float2 a, float2 w) {
    return make_float2(a.x * w.x - a.y * w.y, a.x * w.y + a.y * w.x);
}

// ---------- 640-point Stockham DIF FFT in LDS (radix-5 then 7x radix-2) ----------
// Twiddles via __sincosf (VALU is cheap here). Caller syncs after filling bA.
// Result in bA, natural order. 320 threads.
__device__ void fft640(float2* bA, float2* bB, int t) {
    // radix-5 stage: n=640, s=1, m=128
    if (t < 128) {
        float2 aj[5];
        #pragma unroll
        for (int j = 0; j < 5; ++j) aj[j] = bA[t + 128 * j];
        const float wr[5] = {1.0f, 0.30901699f, -0.80901699f, -0.80901699f, 0.30901699f};
        const float wi[5] = {0.0f, -0.95105652f, -0.58778525f, 0.58778525f, 0.95105652f};
        #pragma unroll
        for (int r = 0; r < 5; ++r) {
            float br = aj[0].x, bi = aj[0].y;
            #pragma unroll
            for (int j = 1; j < 5; ++j) {
                int k = (j * r) % 5;
                br += aj[j].x * wr[k] - aj[j].y * wi[k];
                bi += aj[j].x * wi[k] + aj[j].y * wr[k];
            }
            float sn, cs;
            __sincosf((-TWOPI_F / 640.0f) * (float)(t * r), &sn, &cs);
            bB[5 * t + r] = cmul(make_float2(br, bi), make_float2(cs, sn));
        }
    }
    __syncthreads();
    // 7 radix-2 stages: n = 128..2, s = 5..320
    float2* src = bB;
    float2* dst = bA;
    int n = 128, s = 5;
    #pragma unroll
    for (int st = 0; st < 7; ++st) {
        int m = n >> 1;
        int p = t / s;
        int q = t - p * s;
        float2 a = src[q + s * p];
        float2 b = src[q + s * (p + m)];
        float sn, cs;
        __sincosf((-TWOPI_F) * (float)p / (float)n, &sn, &cs);
        float2 d = make_float2(a.x - b.x, a.y - b.y);
        dst[q + s * (2 * p)]     = make_float2(a.x + b.x, a.y + b.y);
        dst[q + s * (2 * p + 1)] = cmul(d, make_float2(cs, sn));
        float2* tmp = src; src = dst; dst = tmp;
        n = m;
        s <<= 1;
        __syncthreads();
    }
    // 8 stages total -> result in bA
}

// ---------- apodization correction vector (len 320, H==W so one vector) ----------
__global__ void apod_kernel(float* __restrict__ a) {
    int n = threadIdx.x;  // 320 threads
    float apod = 0.0f;
    #pragma unroll
    for (int j = -3; j <= 3; ++j) {
        float kv = kbval((float)j);
        apod += kv * cosf((TWOPI_F * (float)j * ((float)n - 160.0f)) / 640.0f);
    }
    a[n] = 1.0f / apod;
}

// ---------- pass A: row FFT. block (ri, c); writes R[c][ri][q] coalesced ----------
// ri = compact row slot 0..319; image row h = ri<160 ? ri+160 : ri-160
// (grid row r = ri<160 ? ri : ri+320 -- handled in passB placement)
__global__ __launch_bounds__(320)
void passA_kernel(const float* __restrict__ img_r, const float* __restrict__ img_i,
                  const float* __restrict__ sm_r, const float* __restrict__ sm_i,
                  const float* __restrict__ apod, float2* __restrict__ R) {
    __shared__ float2 bA[GSZ], bB[GSZ];
    int ri = blockIdx.x, c = blockIdx.y, t = threadIdx.x;
    int h = (ri < 160) ? ri + 160 : ri - 160;
    int w = (t < 160) ? t + 160 : t - 160;
    float scale = apod[h] * apod[w] * (1.0f / 640.0f);  // includes 1/sqrt(G1*G2)
    float xr = img_r[h * NIMG + w];
    float xi = img_i[h * NIMG + w];
    float sr = sm_r[(c * NIMG + h) * NIMG + w];
    float si = sm_i[(c * NIMG + h) * NIMG + w];
    float vr = (xr * sr - xi * si) * scale;
    float vi = (xr * si + xi * sr) * scale;
    int vnz = (t < 160) ? t : t + 320;   // ifftshifted column position
    int vz  = (t < 160) ? t + 320 : t;
    bA[vnz] = make_float2(vr, vi);
    bA[vz]  = make_float2(0.0f, 0.0f);
    __syncthreads();
    fft640(bA, bB, t);
    float2* out = R + (c * 320 + ri) * GSZ;
    out[t] = bA[t];
    out[t + 320] = bA[t + 320];
}

// ---------- pass T: tiled transpose R[c][ri][q] -> Rt[c][q][ri] ----------
__global__ __launch_bounds__(256)
void passT_kernel(const float2* __restrict__ R, float2* __restrict__ Rt) {
    __shared__ float2 tile[32][33];
    int q0 = blockIdx.x * 32, r0 = blockIdx.y * 32, c = blockIdx.z;
    int tx = threadIdx.x & 31, ty = threadIdx.x >> 5;  // 32 x 8
    #pragma unroll
    for (int k = 0; k < 4; ++k) {
        int r = ty + 8 * k;
        tile[r][tx] = R[(c * 320 + r0 + r) * GSZ + q0 + tx];
    }
    __syncthreads();
    #pragma unroll
    for (int k = 0; k < 4; ++k) {
        int r = ty + 8 * k;  // q_sub
        Rt[(c * GSZ + q0 + r) * 320 + r0 + tx] = tile[tx][r];
    }
}

// ---------- pass B: column FFT, all 12 coils per block; coalesced G writes ----------
// block = q (0..639). Reads Rt[c][q][ri] contiguous. Stages all coils in LDS,
// then writes G[q][p][c] as one contiguous 61440B block.
__global__ __launch_bounds__(320)
void passB_kernel(const float2* __restrict__ Rt, float2* __restrict__ G) {
    __shared__ float2 bA[GSZ], bB[GSZ];
    __shared__ float2 Gs[GSZ * 13];  // [p][c] with stride 13 to dodge bank conflicts
    int q = blockIdx.x, t = threadIdx.x;
    for (int c = 0; c < NC; ++c) {
        float2 val = Rt[(c * GSZ + q) * 320 + t];
        int rnz = (t < 160) ? t : t + 320;   // ifftshifted row position
        int rz  = (t < 160) ? t + 320 : t;
        __syncthreads();  // previous iter's Gs staging reads of bA are done
        bA[rnz] = val;
        bA[rz]  = make_float2(0.0f, 0.0f);
        __syncthreads();
        fft640(bA, bB, t);
        Gs[t * 13 + c]         = bA[t];
        Gs[(t + 320) * 13 + c] = bA[t + 320];
    }
    __syncthreads();
    float2* out = G + q * (GSZ * NC);
    #pragma unroll
    for (int j = 0; j < 24; ++j) {
        int i = t + 320 * j;
        int p = i / 12, c = i - 12 * p;
        out[i] = Gs[p * 13 + c];
    }
}

// ---------- KB tap weights + wrapped indices ----------
__device__ __forceinline__ void taps(float om, float* w, int* idx) {
    float t = fmodf((om * 640.0f) / TWOPI_F, 640.0f);
    if (t < 0.0f) t += 640.0f;
    float base = floorf(t);
    float frac = t - base;
    int ib = (int)base;
    #pragma unroll
    for (int j = 0; j < 6; ++j) {
        w[j] = kbval(frac + (float)(2 - j));  // u = t - (base + j - 2)
        int k = ib + j - 2;
        if (k < 0) k += GSZ;
        if (k >= GSZ) k -= GSZ;
        idx[j] = k;
    }
}

// ---------- interpolation: 6 lanes per sample, 2 coils per lane ----------
// G layout: [v][u][c] float2 -> one (v,u) position = 96B contiguous;
// lane p loads coils {2p,2p+1} as one float4.
__global__ __launch_bounds__(256)
void interp_kernel(const float* __restrict__ kt, const float4* __restrict__ Gf,
                   float2* __restrict__ out) {
    int tid = blockIdx.x * 256 + threadIdx.x;   // 614400 = 2400*256 exactly
    int m = tid / 6;
    int p = tid - 6 * m;                        // coil pair index 0..5
    float w1[6], w2[6];
    int iu[6], iv[6];
    taps(kt[m], w1, iu);        // dim 0 -> u (row frequency)
    taps(kt[MS + m], w2, iv);   // dim 1 -> v (col frequency)
    float a0r = 0.0f, a0i = 0.0f, a1r = 0.0f, a1i = 0.0f;
    #pragma unroll
    for (int j2 = 0; j2 < 6; ++j2) {
        int rb = iv[j2] * (GSZ * NC / 2) + p;   // float4 index base for this v-row
        float b2 = w2[j2];
        #pragma unroll
        for (int j1 = 0; j1 < 6; ++j1) {
            float4 g = Gf[rb + iu[j1] * (NC / 2)];
            float ww = b2 * w1[j1];
            a0r = fmaf(ww, g.x, a0r);
            a0i = fmaf(ww, g.y, a0i);
            a1r = fmaf(ww, g.z, a1r);
            a1i = fmaf(ww, g.w, a1i);
        }
    }
    out[(2 * p) * MS + m]     = make_float2(a0r, a0i);
    out[(2 * p + 1) * MS + m] = make_float2(a1r, a1i);
}

extern "C" void kernel_launch(void* const* d_in, const int* in_sizes, int n_in,
                              void* d_out, int out_size, void* d_ws, size_t ws_size,
                              hipStream_t stream) {
    const float* img_r = (const float*)d_in[0];
    const float* img_i = (const float*)d_in[1];
    const float* sm_r  = (const float*)d_in[2];
    const float* sm_i  = (const float*)d_in[3];
    const float* kt    = (const float*)d_in[4];

    // ws layout (~59MB): apod | Rt (19.66MB) | R (19.66MB, reused as G 39.3MB)
    char* ws = (char*)d_ws;
    float*  apod = (float*)ws;                                    // 320 floats
    float2* Rt   = (float2*)(ws + 2048);                          // 12*640*320*8
    float2* R    = (float2*)(ws + 2048 + 12 * GSZ * 320 * 8);     // 12*320*640*8
    float2* G    = R;                                             // reuse: R dead after passT

    apod_kernel<<<1, 320, 0, stream>>>(apod);
    passA_kernel<<<dim3(320, NC), 320, 0, stream>>>(img_r, img_i, sm_r, sm_i, apod, R);
    passT_kernel<<<dim3(20, 10, NC), 256, 0, stream>>>(R, Rt);
    passB_kernel<<<GSZ, 320, 0, stream>>>(Rt, G);
    interp_kernel<<<2400, 256, 0, stream>>>(kt, (const float4*)G, (float2*)d_out);
}

// Round 4
// 178.095 us; speedup vs baseline: 1.5237x; 1.1829x over previous
//
#include <hip/hip_runtime.h>

#define GSZ 640
#define NIMG 320
#define MS 102400
#define NC 12
#define BETA_F 13.8551004f
#define TWOPI_F 6.2831855f

// ---------- Bessel I0 (Abramowitz & Stegun 9.8.1 / 9.8.2, rel err < 2e-7) ----------
__device__ __forceinline__ float i0f(float x) {
    float ax = fabsf(x);
    if (ax < 3.75f) {
        float t = ax * (1.0f / 3.75f);
        t *= t;
        return 1.0f + t * (3.5156229f + t * (3.0899424f + t * (1.2067492f +
                     t * (0.2659732f + t * (0.0360768f + t * 0.0045813f)))));
    } else {
        float t = 3.75f / ax;
        float p = 0.39894228f + t * (0.01328592f + t * (0.00225319f + t * (-0.00157565f +
                  t * (0.00916281f + t * (-0.02057706f + t * (0.02635537f +
                  t * (-0.01647633f + t * 0.00392377f)))))));
        return p * expf(ax) / sqrtf(ax);
    }
}

// Kaiser-Bessel kernel, support |u| <= 3 (J=6)
__device__ __forceinline__ float kbval(float u) {
    float mm = fabsf(u) * (1.0f / 3.0f);
    float s = 1.0f - mm * mm;
    s = s > 0.0f ? s : 0.0f;
    float v = i0f(BETA_F * sqrtf(s)) * (1.0f / 6.0f);
    return (mm <= 1.0f) ? v : 0.0f;
}

__device__ __forceinline__ float2 cmul(float2 a, float2 w) {
    return make_float2(a.x * w.x - a.y * w.y, a.x * w.y + a.y * w.x);
}

// Stockham DIF radix-4 stage: 160 butterflies, call with t < 160.
// src[q + s(p + m j)] -> dst[q + s(4p + k)] * w_n^{pk},  m = n/4.
__device__ __forceinline__ void radix4_stage(const float2* src, float2* dst,
                                             int t, int s, int n) {
    int p = t / s, q = t - p * s;
    int m = n >> 2;
    float2 a0 = src[q + s * p];
    float2 a1 = src[q + s * (p + m)];
    float2 a2 = src[q + s * (p + 2 * m)];
    float2 a3 = src[q + s * (p + 3 * m)];
    float2 e = make_float2(a0.x + a2.x, a0.y + a2.y);
    float2 f = make_float2(a1.x + a3.x, a1.y + a3.y);
    float2 g = make_float2(a0.x - a2.x, a0.y - a2.y);
    float2 h = make_float2(a1.x - a3.x, a1.y - a3.y);
    float2 B0 = make_float2(e.x + f.x, e.y + f.y);
    float2 B2 = make_float2(e.x - f.x, e.y - f.y);
    float2 mih = make_float2(h.y, -h.x);                 // -i*h
    float2 B1 = make_float2(g.x + mih.x, g.y + mih.y);
    float2 B3 = make_float2(g.x - mih.x, g.y - mih.y);
    float ang = (-TWOPI_F) * (float)p / (float)n;
    float s1, c1, s2, c2, s3, c3;
    __sincosf(ang, &s1, &c1);
    __sincosf(2.0f * ang, &s2, &c2);
    __sincosf(3.0f * ang, &s3, &c3);
    dst[q + s * (4 * p)]     = B0;
    dst[q + s * (4 * p + 1)] = cmul(B1, make_float2(c1, s1));
    dst[q + s * (4 * p + 2)] = cmul(B2, make_float2(c2, s2));
    dst[q + s * (4 * p + 3)] = cmul(B3, make_float2(c3, s3));
}

// ---------- 640-point FFT: radix-5, 3x radix-4 (LDS), final radix-2 in regs ----------
// Caller fills bA[0..639]; results: thread t gets X[t] in *olo, X[t+320] in *ohi.
// 4 internal syncs. 320 threads.
__device__ void fft640(float2* bA, float2* bB, int t, float2* olo, float2* ohi) {
    __syncthreads();   // bA ready
    // stage 0: radix-5, n=640, s=1 (t < 128):  bA -> bB
    if (t < 128) {
        float2 aj[5];
        #pragma unroll
        for (int j = 0; j < 5; ++j) aj[j] = bA[t + 128 * j];
        const float wr[5] = {1.0f, 0.30901699f, -0.80901699f, -0.80901699f, 0.30901699f};
        const float wi[5] = {0.0f, -0.95105652f, -0.58778525f, 0.58778525f, 0.95105652f};
        #pragma unroll
        for (int r = 0; r < 5; ++r) {
            float br = aj[0].x, bi = aj[0].y;
            #pragma unroll
            for (int j = 1; j < 5; ++j) {
                int k = (j * r) % 5;
                br += aj[j].x * wr[k] - aj[j].y * wi[k];
                bi += aj[j].x * wi[k] + aj[j].y * wr[k];
            }
            float sn, cs;
            __sincosf((-TWOPI_F / 640.0f) * (float)(t * r), &sn, &cs);
            bB[5 * t + r] = cmul(make_float2(br, bi), make_float2(cs, sn));
        }
    }
    __syncthreads();
    // stage 1: radix-4, n=128, s=5:  bB -> bA
    if (t < 160) radix4_stage(bB, bA, t, 5, 128);
    __syncthreads();
    // stage 2: radix-4, n=32, s=20:  bA -> bB
    if (t < 160) radix4_stage(bA, bB, t, 20, 32);
    __syncthreads();
    // stage 3: radix-4, n=8, s=80:  bB -> bA
    if (t < 160) radix4_stage(bB, bA, t, 80, 8);
    __syncthreads();
    // stage 4: radix-2, n=2, s=320, twiddle = 1 -- in registers
    float2 a = bA[t], b = bA[t + 320];
    *olo = make_float2(a.x + b.x, a.y + b.y);
    *ohi = make_float2(a.x - b.x, a.y - b.y);
}

// ---------- apodization correction vector (len 320, H==W so one vector) ----------
__global__ void apod_kernel(float* __restrict__ a) {
    int n = threadIdx.x;  // 320 threads
    float apod = 0.0f;
    #pragma unroll
    for (int j = -3; j <= 3; ++j) {
        float kv = kbval((float)j);
        apod += kv * cosf((TWOPI_F * (float)j * ((float)n - 160.0f)) / 640.0f);
    }
    a[n] = 1.0f / apod;
}

// ---------- pass A: row FFT. block (ri, c); writes R[c][ri][q] coalesced ----------
__global__ __launch_bounds__(320)
void passA_kernel(const float* __restrict__ img_r, const float* __restrict__ img_i,
                  const float* __restrict__ sm_r, const float* __restrict__ sm_i,
                  const float* __restrict__ apod, float2* __restrict__ R) {
    __shared__ float2 bA[GSZ], bB[GSZ];
    int ri = blockIdx.x, c = blockIdx.y, t = threadIdx.x;
    int h = (ri < 160) ? ri + 160 : ri - 160;
    int w = (t < 160) ? t + 160 : t - 160;
    float scale = apod[h] * apod[w] * (1.0f / 640.0f);  // includes 1/sqrt(G1*G2)
    float xr = img_r[h * NIMG + w];
    float xi = img_i[h * NIMG + w];
    float sr = sm_r[(c * NIMG + h) * NIMG + w];
    float si = sm_i[(c * NIMG + h) * NIMG + w];
    float vr = (xr * sr - xi * si) * scale;
    float vi = (xr * si + xi * sr) * scale;
    int vnz = (t < 160) ? t : t + 320;   // ifftshifted column position
    int vz  = (t < 160) ? t + 320 : t;
    bA[vnz] = make_float2(vr, vi);
    bA[vz]  = make_float2(0.0f, 0.0f);
    float2 lo, hi;
    fft640(bA, bB, t, &lo, &hi);
    float2* out = R + (c * 320 + ri) * GSZ;
    out[t] = lo;
    out[t + 320] = hi;
}

// ---------- pass T: tiled transpose R[c][ri][q] -> Rt[c][q][ri] ----------
__global__ __launch_bounds__(256)
void passT_kernel(const float2* __restrict__ R, float2* __restrict__ Rt) {
    __shared__ float2 tile[32][33];
    int q0 = blockIdx.x * 32, r0 = blockIdx.y * 32, c = blockIdx.z;
    int tx = threadIdx.x & 31, ty = threadIdx.x >> 5;  // 32 x 8
    #pragma unroll
    for (int k = 0; k < 4; ++k) {
        int r = ty + 8 * k;
        tile[r][tx] = R[(c * 320 + r0 + r) * GSZ + q0 + tx];
    }
    __syncthreads();
    #pragma unroll
    for (int k = 0; k < 4; ++k) {
        int r = ty + 8 * k;  // q_sub
        Rt[(c * GSZ + q0 + r) * 320 + r0 + tx] = tile[tx][r];
    }
}

// ---------- pass B1: column FFT per (q,c); writes F[c][q][u] coalesced ----------
__global__ __launch_bounds__(320)
void passB1_kernel(const float2* __restrict__ Rt, float2* __restrict__ F) {
    __shared__ float2 bA[GSZ], bB[GSZ];
    int q = blockIdx.x, c = blockIdx.y, t = threadIdx.x;
    float2 val = Rt[(c * GSZ + q) * 320 + t];   // contiguous in t
    int rnz = (t < 160) ? t : t + 320;   // ifftshifted row position
    int rz  = (t < 160) ? t + 320 : t;
    bA[rnz] = val;
    bA[rz]  = make_float2(0.0f, 0.0f);
    float2 lo, hi;
    fft640(bA, bB, t, &lo, &hi);
    float2* out = F + (c * GSZ + q) * GSZ;
    out[t] = lo;
    out[t + 320] = hi;
}

// ---------- pass B2: LDS-tiled shuffle F[c][q][u] -> G[q][u][c] ----------
__global__ __launch_bounds__(320)
void passB2_kernel(const float2* __restrict__ F, float2* __restrict__ G) {
    __shared__ float2 Ls[NC][321];
    int q = blockIdx.x, u0 = blockIdx.y * 320, t = threadIdx.x;
    #pragma unroll
    for (int c = 0; c < NC; ++c)
        Ls[c][t] = F[(c * GSZ + q) * GSZ + u0 + t];
    __syncthreads();
    float2* out = G + (q * GSZ + u0) * NC;
    #pragma unroll
    for (int j = 0; j < NC; ++j) {
        int i = t + 320 * j;
        int u = i / 12, c = i - 12 * u;
        out[i] = Ls[c][u];
    }
}

// ---------- KB tap weights + wrapped indices ----------
__device__ __forceinline__ void taps(float om, float* w, int* idx) {
    float t = fmodf((om * 640.0f) / TWOPI_F, 640.0f);
    if (t < 0.0f) t += 640.0f;
    float base = floorf(t);
    float frac = t - base;
    int ib = (int)base;
    #pragma unroll
    for (int j = 0; j < 6; ++j) {
        w[j] = kbval(frac + (float)(2 - j));  // u = t - (base + j - 2)
        int k = ib + j - 2;
        if (k < 0) k += GSZ;
        if (k >= GSZ) k -= GSZ;
        idx[j] = k;
    }
}

// ---------- interpolation: 6 lanes per sample, 2 coils per lane ----------
// G layout: [v][u][c] float2 -> one (v,u) position = 96B contiguous;
// lane p loads coils {2p,2p+1} as one float4.
__global__ __launch_bounds__(256)
void interp_kernel(const float* __restrict__ kt, const float4* __restrict__ Gf,
                   float2* __restrict__ out) {
    int tid = blockIdx.x * 256 + threadIdx.x;   // 614400 = 2400*256 exactly
    int m = tid / 6;
    int p = tid - 6 * m;                        // coil pair index 0..5
    float w1[6], w2[6];
    int iu[6], iv[6];
    taps(kt[m], w1, iu);        // dim 0 -> u (row frequency)
    taps(kt[MS + m], w2, iv);   // dim 1 -> v (col frequency)
    float a0r = 0.0f, a0i = 0.0f, a1r = 0.0f, a1i = 0.0f;
    #pragma unroll
    for (int j2 = 0; j2 < 6; ++j2) {
        int rb = iv[j2] * (GSZ * NC / 2) + p;   // float4 index base for this v-row
        float b2 = w2[j2];
        #pragma unroll
        for (int j1 = 0; j1 < 6; ++j1) {
            float4 g = Gf[rb + iu[j1] * (NC / 2)];
            float ww = b2 * w1[j1];
            a0r = fmaf(ww, g.x, a0r);
            a0i = fmaf(ww, g.y, a0i);
            a1r = fmaf(ww, g.z, a1r);
            a1i = fmaf(ww, g.w, a1i);
        }
    }
    out[(2 * p) * MS + m]     = make_float2(a0r, a0i);
    out[(2 * p + 1) * MS + m] = make_float2(a1r, a1i);
}

extern "C" void kernel_launch(void* const* d_in, const int* in_sizes, int n_in,
                              void* d_out, int out_size, void* d_ws, size_t ws_size,
                              hipStream_t stream) {
    const float* img_r = (const float*)d_in[0];
    const float* img_i = (const float*)d_in[1];
    const float* sm_r  = (const float*)d_in[2];
    const float* sm_i  = (const float*)d_in[3];
    const float* kt    = (const float*)d_in[4];

    // ws layout (~79MB): apod | [R 19.66M][Rt 19.66M][F 39.32M]; G overlays R+Rt
    // lifetime chain: R(passA) -> Rt(passT; R dead) -> F(passB1; Rt dead)
    //                 -> G(passB2 reads F, writes over dead R+Rt)
    char* ws = (char*)d_ws;
    float*  apod = (float*)ws;                                 // 320 floats
    char* base = ws + 2048;
    float2* R  = (float2*)base;                                // 12*320*640*8
    float2* Rt = (float2*)(base + 19660800);                   // 12*640*320*8
    float2* F  = (float2*)(base + 39321600);                   // 12*640*640*8
    float2* G  = (float2*)base;                                // 640*640*12*8

    apod_kernel<<<1, 320, 0, stream>>>(apod);
    passA_kernel<<<dim3(320, NC), 320, 0, stream>>>(img_r, img_i, sm_r, sm_i, apod, R);
    passT_kernel<<<dim3(20, 10, NC), 256, 0, stream>>>(R, Rt);
    passB1_kernel<<<dim3(GSZ, NC), 320, 0, stream>>>(Rt, F);
    passB2_kernel<<<dim3(GSZ, 2), 320, 0, stream>>>(F, G);
    interp_kernel<<<2400, 256, 0, stream>>>(kt, (const float4*)G, (float2*)d_out);
}

// Round 6
// 172.390 us; speedup vs baseline: 1.5741x; 1.0331x over previous
//
#include <hip/hip_runtime.h>
#include <hip/hip_fp16.h>

#define GSZ 640
#define NIMG 320
#define MS 102400
#define NC 12
#define BETA_F 13.8551004f
#define TWOPI_F 6.2831855f
// fp16 grid scaling: G is ~1e-9..1e-10 in the reference's un-normalized KB
// convention (weights ~1e4 each restore it). Store G*2^24 in fp16, fold 2^-24
// into the interp weights -- cancels exactly, keeps fp16 in its normal range.
#define GSC 16777216.0f
#define GSC_INV 5.9604645e-8f

// ---------- Bessel I0 (Abramowitz & Stegun 9.8.1 / 9.8.2, rel err < 2e-7) ----------
__device__ __forceinline__ float i0f(float x) {
    float ax = fabsf(x);
    if (ax < 3.75f) {
        float t = ax * (1.0f / 3.75f);
        t *= t;
        return 1.0f + t * (3.5156229f + t * (3.0899424f + t * (1.2067492f +
                     t * (0.2659732f + t * (0.0360768f + t * 0.0045813f)))));
    } else {
        float t = 3.75f / ax;
        float p = 0.39894228f + t * (0.01328592f + t * (0.00225319f + t * (-0.00157565f +
                  t * (0.00916281f + t * (-0.02057706f + t * (0.02635537f +
                  t * (-0.01647633f + t * 0.00392377f)))))));
        return p * expf(ax) / sqrtf(ax);
    }
}

// Kaiser-Bessel kernel, support |u| <= 3 (J=6)
__device__ __forceinline__ float kbval(float u) {
    float mm = fabsf(u) * (1.0f / 3.0f);
    float s = 1.0f - mm * mm;
    s = s > 0.0f ? s : 0.0f;
    float v = i0f(BETA_F * sqrtf(s)) * (1.0f / 6.0f);
    return (mm <= 1.0f) ? v : 0.0f;
}

// image-domain apodization correction at pixel n (0..319)
__device__ __forceinline__ float apodval(int n) {
    float s = 0.0f;
    #pragma unroll
    for (int j = -3; j <= 3; ++j) {
        s += kbval((float)j) * cosf((TWOPI_F * (float)j * ((float)n - 160.0f)) / 640.0f);
    }
    return 1.0f / s;
}

__device__ __forceinline__ float2 cmul(float2 a, float2 w) {
    return make_float2(a.x * w.x - a.y * w.y, a.x * w.y + a.y * w.x);
}

// Stockham DIF radix-4 stage: 160 butterflies, call with t < 160.
__device__ __forceinline__ void radix4_stage(const float2* src, float2* dst,
                                             int t, int s, int n) {
    int p = t / s, q = t - p * s;
    int m = n >> 2;
    float2 a0 = src[q + s * p];
    float2 a1 = src[q + s * (p + m)];
    float2 a2 = src[q + s * (p + 2 * m)];
    float2 a3 = src[q + s * (p + 3 * m)];
    float2 e = make_float2(a0.x + a2.x, a0.y + a2.y);
    float2 f = make_float2(a1.x + a3.x, a1.y + a3.y);
    float2 g = make_float2(a0.x - a2.x, a0.y - a2.y);
    float2 h = make_float2(a1.x - a3.x, a1.y - a3.y);
    float2 B0 = make_float2(e.x + f.x, e.y + f.y);
    float2 B2 = make_float2(e.x - f.x, e.y - f.y);
    float2 mih = make_float2(h.y, -h.x);                 // -i*h
    float2 B1 = make_float2(g.x + mih.x, g.y + mih.y);
    float2 B3 = make_float2(g.x - mih.x, g.y - mih.y);
    float ang = (-TWOPI_F) * (float)p / (float)n;
    float s1, c1, s2, c2, s3, c3;
    __sincosf(ang, &s1, &c1);
    __sincosf(2.0f * ang, &s2, &c2);
    __sincosf(3.0f * ang, &s3, &c3);
    dst[q + s * (4 * p)]     = B0;
    dst[q + s * (4 * p + 1)] = cmul(B1, make_float2(c1, s1));
    dst[q + s * (4 * p + 2)] = cmul(B2, make_float2(c2, s2));
    dst[q + s * (4 * p + 3)] = cmul(B3, make_float2(c3, s3));
}

// ---------- 640-point FFT: radix-5, 3x radix-4 (LDS), final radix-2 in regs ----------
// Engine-local: bA/bB are this engine's 640-elem buffers, t in [0,320).
// __syncthreads() is block-wide; co-resident engines stay in lockstep.
__device__ void fft640(float2* bA, float2* bB, int t, float2* olo, float2* ohi) {
    __syncthreads();   // bA ready
    if (t < 128) {
        float2 aj[5];
        #pragma unroll
        for (int j = 0; j < 5; ++j) aj[j] = bA[t + 128 * j];
        const float wr[5] = {1.0f, 0.30901699f, -0.80901699f, -0.80901699f, 0.30901699f};
        const float wi[5] = {0.0f, -0.95105652f, -0.58778525f, 0.58778525f, 0.95105652f};
        #pragma unroll
        for (int r = 0; r < 5; ++r) {
            float br = aj[0].x, bi = aj[0].y;
            #pragma unroll
            for (int j = 1; j < 5; ++j) {
                int k = (j * r) % 5;
                br += aj[j].x * wr[k] - aj[j].y * wi[k];
                bi += aj[j].x * wi[k] + aj[j].y * wr[k];
            }
            float sn, cs;
            __sincosf((-TWOPI_F / 640.0f) * (float)(t * r), &sn, &cs);
            bB[5 * t + r] = cmul(make_float2(br, bi), make_float2(cs, sn));
        }
    }
    __syncthreads();
    if (t < 160) radix4_stage(bB, bA, t, 5, 128);
    __syncthreads();
    if (t < 160) radix4_stage(bA, bB, t, 20, 32);
    __syncthreads();
    if (t < 160) radix4_stage(bB, bA, t, 80, 8);
    __syncthreads();
    float2 a = bA[t], b = bA[t + 320];
    *olo = make_float2(a.x + b.x, a.y + b.y);
    *ohi = make_float2(a.x - b.x, a.y - b.y);
}

// ---------- pass A: row FFT, 2 rows/block (2 engines x 320 threads) ----------
// apod fused. Writes R[c][ri][q] coalesced (rows ri0, ri0+1 contiguous).
__global__ __launch_bounds__(640)
void passA_kernel(const float* __restrict__ img_r, const float* __restrict__ img_i,
                  const float* __restrict__ sm_r, const float* __restrict__ sm_i,
                  float2* __restrict__ R) {
    __shared__ float2 bA[2][GSZ], bB[2][GSZ];
    int e = threadIdx.x >= 320;
    int t = threadIdx.x - 320 * e;
    int ri = 2 * blockIdx.x + e, c = blockIdx.y;
    int h = (ri < 160) ? ri + 160 : ri - 160;
    int w = (t < 160) ? t + 160 : t - 160;
    float scale = apodval(h) * apodval(w) * (1.0f / 640.0f);  // incl. 1/sqrt(G1*G2)
    float xr = img_r[h * NIMG + w];
    float xi = img_i[h * NIMG + w];
    float sr = sm_r[(c * NIMG + h) * NIMG + w];
    float si = sm_i[(c * NIMG + h) * NIMG + w];
    float vr = (xr * sr - xi * si) * scale;
    float vi = (xr * si + xi * sr) * scale;
    int vnz = (t < 160) ? t : t + 320;   // ifftshifted column position
    int vz  = (t < 160) ? t + 320 : t;
    bA[e][vnz] = make_float2(vr, vi);
    bA[e][vz]  = make_float2(0.0f, 0.0f);
    float2 lo, hi;
    fft640(bA[e], bB[e], t, &lo, &hi);
    float2* out = R + (c * 320 + ri) * GSZ;
    out[t] = lo;
    out[t + 320] = hi;
}

// ---------- pass T: tiled transpose R[c][ri][q] -> Rt[c][q][ri] ----------
__global__ __launch_bounds__(256)
void passT_kernel(const float2* __restrict__ R, float2* __restrict__ Rt) {
    __shared__ float2 tile[32][33];
    int q0 = blockIdx.x * 32, r0 = blockIdx.y * 32, c = blockIdx.z;
    int tx = threadIdx.x & 31, ty = threadIdx.x >> 5;  // 32 x 8
    #pragma unroll
    for (int k = 0; k < 4; ++k) {
        int r = ty + 8 * k;
        tile[r][tx] = R[(c * 320 + r0 + r) * GSZ + q0 + tx];
    }
    __syncthreads();
    #pragma unroll
    for (int k = 0; k < 4; ++k) {
        int r = ty + 8 * k;  // q_sub
        Rt[(c * GSZ + q0 + r) * 320 + r0 + tx] = tile[tx][r];
    }
}

// ---------- pass B1: column FFT, 2 q/block; writes F[c][q][u] coalesced ----------
__global__ __launch_bounds__(640)
void passB1_kernel(const float2* __restrict__ Rt, float2* __restrict__ F) {
    __shared__ float2 bA[2][GSZ], bB[2][GSZ];
    int e = threadIdx.x >= 320;
    int t = threadIdx.x - 320 * e;
    int q0 = 2 * blockIdx.x, c = blockIdx.y;
    // engine e handles q = q0+e; combined read is one contiguous 640-elem run
    float2 val = Rt[(c * GSZ + q0) * 320 + threadIdx.x];
    int rnz = (t < 160) ? t : t + 320;   // ifftshifted row position
    int rz  = (t < 160) ? t + 320 : t;
    bA[e][rnz] = val;
    bA[e][rz]  = make_float2(0.0f, 0.0f);
    float2 lo, hi;
    fft640(bA[e], bB[e], t, &lo, &hi);
    float2* out = F + (c * GSZ + q0 + e) * GSZ;
    out[t] = lo;
    out[t + 320] = hi;
}

// ---------- pass B2: shuffle F[c][q][u] -> G[q][u][c], scale by GSC, fp16 ----------
// G element (v,u): 12 coils x (re,im) half = 48B. One block writes 15360B contiguous.
__global__ __launch_bounds__(320)
void passB2_kernel(const float2* __restrict__ F, unsigned int* __restrict__ G) {
    __shared__ float2 Ls[NC][321];
    int q = blockIdx.x, u0 = blockIdx.y * 320, t = threadIdx.x;
    #pragma unroll
    for (int c = 0; c < NC; ++c)
        Ls[c][t] = F[(c * GSZ + q) * GSZ + u0 + t];
    __syncthreads();
    unsigned int* out = G + (q * GSZ + u0) * NC;  // NC uint words per u
    #pragma unroll
    for (int j = 0; j < NC; ++j) {
        int i = t + 320 * j;       // 0..3839
        int u = i / 12, c = i - 12 * u;
        float2 v = Ls[c][u];
        __half2 h = __float22half2_rn(make_float2(v.x * GSC, v.y * GSC));
        out[i] = *(const unsigned int*)&h;
    }
}

// ---------- KB tap weights + wrapped indices ----------
__device__ __forceinline__ void taps(float om, float* w, int* idx) {
    float t = fmodf((om * 640.0f) / TWOPI_F, 640.0f);
    if (t < 0.0f) t += 640.0f;
    float base = floorf(t);
    float frac = t - base;
    int ib = (int)base;
    #pragma unroll
    for (int j = 0; j < 6; ++j) {
        w[j] = kbval(frac + (float)(2 - j));  // u = t - (base + j - 2)
        int k = ib + j - 2;
        if (k < 0) k += GSZ;
        if (k >= GSZ) k -= GSZ;
        idx[j] = k;
    }
}

struct __align__(8) h2x2 { __half2 a, b; };  // 2 coils: (re,im),(re,im)

// ---------- interpolation: 6 lanes per sample, 2 coils per lane, fp16 grid ----------
__global__ __launch_bounds__(256)
void interp_kernel(const float* __restrict__ kt, const h2x2* __restrict__ Gp,
                   float2* __restrict__ out) {
    int tid = blockIdx.x * 256 + threadIdx.x;   // 614400 = 2400*256 exactly
    int m = tid / 6;
    int p = tid - 6 * m;                        // coil pair index 0..5
    float w1[6], w2[6];
    int iu[6], iv[6];
    taps(kt[m], w1, iu);        // dim 0 -> u (row frequency)
    taps(kt[MS + m], w2, iv);   // dim 1 -> v (col frequency)
    #pragma unroll
    for (int j = 0; j < 6; ++j) w2[j] *= GSC_INV;   // undo the fp16 grid scaling
    float a0r = 0.0f, a0i = 0.0f, a1r = 0.0f, a1i = 0.0f;
    #pragma unroll
    for (int j2 = 0; j2 < 6; ++j2) {
        int rb = iv[j2] * (GSZ * 6) + p;        // h2x2 index base for this v-row
        float b2 = w2[j2];
        #pragma unroll
        for (int j1 = 0; j1 < 6; ++j1) {
            h2x2 g = Gp[rb + iu[j1] * 6];
            float2 f0 = __half22float2(g.a);
            float2 f1 = __half22float2(g.b);
            float ww = b2 * w1[j1];
            a0r = fmaf(ww, f0.x, a0r);
            a0i = fmaf(ww, f0.y, a0i);
            a1r = fmaf(ww, f1.x, a1r);
            a1i = fmaf(ww, f1.y, a1i);
        }
    }
    out[(2 * p) * MS + m]     = make_float2(a0r, a0i);
    out[(2 * p + 1) * MS + m] = make_float2(a1r, a1i);
}

extern "C" void kernel_launch(void* const* d_in, const int* in_sizes, int n_in,
                              void* d_out, int out_size, void* d_ws, size_t ws_size,
                              hipStream_t stream) {
    const float* img_r = (const float*)d_in[0];
    const float* img_i = (const float*)d_in[1];
    const float* sm_r  = (const float*)d_in[2];
    const float* sm_i  = (const float*)d_in[3];
    const float* kt    = (const float*)d_in[4];

    // ws layout (~79MB): [R 19.66M][Rt 19.66M][F 39.32M]; G(fp16, 19.66M) overlays R
    // lifetimes: R(passA) -> Rt(passT) -> F(passB1) -> G(passB2; R dead)
    char* base = (char*)d_ws;
    float2* R  = (float2*)base;                                // 12*320*640*8
    float2* Rt = (float2*)(base + 19660800);                   // 12*640*320*8
    float2* F  = (float2*)(base + 39321600);                   // 12*640*640*8
    unsigned int* G = (unsigned int*)base;                     // 640*640*12*4 (fp16 pairs)

    passA_kernel<<<dim3(160, NC), 640, 0, stream>>>(img_r, img_i, sm_r, sm_i, R);
    passT_kernel<<<dim3(20, 10, NC), 256, 0, stream>>>(R, Rt);
    passB1_kernel<<<dim3(320, NC), 640, 0, stream>>>(Rt, F);
    passB2_kernel<<<dim3(GSZ, 2), 320, 0, stream>>>(F, G);
    interp_kernel<<<2400, 256, 0, stream>>>(kt, (const h2x2*)G, (float2*)d_out);
}